// Round 5
// baseline (39691.391 us; speedup 1.0000x reference)
//
#include <hip/hip_runtime.h>
#include <hip/hip_bf16.h>

// Leaky 2-layer CTRNN, B=64 T=512 D_IN=256 H=1024 D_OUT=256, alpha=0.1.
// Round 7: spill-proof by construction — 4h x 4b tile, 16-wide k-split.
//  History: rounds 3-5 all pinned VGPR_Count at exactly 128 (the backend's
//  budget for 512-thr blocks; launch_bounds 2nd arg didn't change it) and
//  spilled the 4h x 8b acc tile (~136 scratch dwords/thread/phase, WRITE
//  36.7GB vs 267MB logical). Round 6 tried amdgpu_waves_per_eu(2) and the
//  container died twice (infra vs attr: unresolved) -> drop the attribute,
//  shrink the tile instead: acc = 16 v2f = 32 VGPRs, peak live ~85 < 128.
//  Thread coords: ks=tid&15 (k-slice), hp=(tid>>4)&1 (4-row half),
//  bp=tid>>5 (4-batch group); k = 4*ks + 64*j, j=0..15.
//   - w rows XOR-swizzled (c16 ^ ((c16>>3)&7)); measured ~0 conflicts
//   - partials: in-wave fold (__shfl_xor 1) -> 8 cols, [512][9] LDS
//   - owner mapping (h=tid&7, b=tid>>3), v-carry, agent-relaxed tree barrier
//     unchanged since round 2 (verified passing).

using v2f = __attribute__((ext_vector_type(2))) float;

constexpr int Bsz = 64, Tlen = 512, DIN = 256, Hdim = 1024, DOUT = 256;
constexpr int NBLK = 256;           // persistent, 1 per CU
constexpr int NTHR = 512;           // 8 waves
constexpr int CH = 8;               // h rows per block
constexpr int TH = Tlen * Hdim;     // per-batch state stride (floats)
constexpr int PROW = 9;             // partial-buffer row stride (odd: bank-clean)

__device__ __forceinline__ void gbarrier(unsigned* bar, unsigned phase) {
  __builtin_amdgcn_s_waitcnt(0);            // every thread drains its sc1 stores
  __syncthreads();
  if (threadIdx.x == 0) {
    unsigned* leaf = bar + 32 + (blockIdx.x & 31) * 32;   // 128B-padded leaves
    unsigned old = __hip_atomic_fetch_add(leaf, 1u, __ATOMIC_RELAXED,
                                          __HIP_MEMORY_SCOPE_AGENT);
    if ((old & 7u) == 7u)                   // 8th arrival at this leaf this phase
      __hip_atomic_fetch_add(bar, 1u, __ATOMIC_RELAXED, __HIP_MEMORY_SCOPE_AGENT);
    while (__hip_atomic_load(bar, __ATOMIC_RELAXED, __HIP_MEMORY_SCOPE_AGENT) <
           phase * 32u)
      __builtin_amdgcn_s_sleep(4);
    __builtin_amdgcn_fence(__ATOMIC_ACQUIRE, "agent");  // one buffer_inv
  }
  __syncthreads();
}

// ---- macro-generated 4h x 4b register tile: NAMED accumulators only ----
#define FOR_BI(M) M(0) M(1) M(2) M(3)

#define DECL_ACC(bi)                                                   \
  v2f a0##bi = {0.f, 0.f}, a1##bi = {0.f, 0.f},                        \
      a2##bi = {0.f, 0.f}, a3##bi = {0.f, 0.f};

#define STEP(bi) {                                                     \
    const float4 fq = *(const float4*)(fp0 + (size_t)bi * TH);         \
    const v2f fxy = {fq.x, fq.y}, fzw = {fq.z, fq.w};                  \
    a0##bi = __builtin_elementwise_fma(w0xy, fxy, a0##bi);             \
    a0##bi = __builtin_elementwise_fma(w0zw, fzw, a0##bi);             \
    a1##bi = __builtin_elementwise_fma(w1xy, fxy, a1##bi);             \
    a1##bi = __builtin_elementwise_fma(w1zw, fzw, a1##bi);             \
    a2##bi = __builtin_elementwise_fma(w2xy, fxy, a2##bi);             \
    a2##bi = __builtin_elementwise_fma(w2zw, fzw, a2##bi);             \
    a3##bi = __builtin_elementwise_fma(w3xy, fxy, a3##bi);             \
    a3##bi = __builtin_elementwise_fma(w3zw, fzw, a3##bi);             \
  }

// one full dot over K=1024: k in {4*ks + 64*j + 0..3 : j=0..15}
#define DOT_TILE(wb, frp) {                                            \
    _Pragma("unroll")                                                  \
    for (int j = 0; j < 16; ++j) {                                     \
      const int c16 = ks + 16 * j;                                     \
      const int phys = c16 ^ ((c16 >> 3) & 7);                         \
      const float* wp = (wb) + phys * 4;                               \
      const float4 w0q = *(const float4*)(wp);                         \
      const float4 w1q = *(const float4*)(wp + 1024);                  \
      const float4 w2q = *(const float4*)(wp + 2048);                  \
      const float4 w3q = *(const float4*)(wp + 3072);                  \
      const v2f w0xy = {w0q.x, w0q.y}, w0zw = {w0q.z, w0q.w};          \
      const v2f w1xy = {w1q.x, w1q.y}, w1zw = {w1q.z, w1q.w};          \
      const v2f w2xy = {w2q.x, w2q.y}, w2zw = {w2q.z, w2q.w};          \
      const v2f w3xy = {w3q.x, w3q.y}, w3zw = {w3q.z, w3q.w};          \
      const float* fp0 = (frp) + 4 * ks + 64 * j;                      \
      FOR_BI(STEP)                                                     \
    }                                                                  \
  }

// fold ks pairs in-wave (DPP), scatter folded partials to [512][PROW] LDS
#define FOLD(bi) {                                                     \
    float* pr = smP + ((4 * bp + bi) * 8 + 4 * hp) * PROW + col;       \
    float s0 = a0##bi.x + a0##bi.y; s0 += __shfl_xor(s0, 1);           \
    float s1 = a1##bi.x + a1##bi.y; s1 += __shfl_xor(s1, 1);           \
    float s2 = a2##bi.x + a2##bi.y; s2 += __shfl_xor(s2, 1);           \
    float s3 = a3##bi.x + a3##bi.y; s3 += __shfl_xor(s3, 1);           \
    if (wrp) {                                                         \
      pr[0 * PROW] = s0; pr[1 * PROW] = s1;                            \
      pr[2 * PROW] = s2; pr[3 * PROW] = s3;                            \
    }                                                                  \
  }

__device__ __forceinline__ float gather8(const float* __restrict__ prow) {
  float s0 = prow[0] + prow[1], s1 = prow[2] + prow[3];
  float s2 = prow[4] + prow[5], s3 = prow[6] + prow[7];
  return (s0 + s1) + (s2 + s3);
}

__global__ void __launch_bounds__(NTHR)
rnn_recurrent(const float* __restrict__ Wrec0, const float* __restrict__ Wrec1,
              const float* __restrict__ Win1,  const float* __restrict__ b1,
              const __hip_bfloat16* __restrict__ X0,
              float* __restrict__ states0, float* __restrict__ states1,
              unsigned* __restrict__ bar) {
  extern __shared__ float smW[];  // [nrows][1024] swizzled w, then [512][9] partials
  const int bid = blockIdx.x, tid = threadIdx.x;
  const bool isL1 = bid >= NBLK / 2;
  const int c = bid & (NBLK / 2 - 1);       // h chunk 0..127

  // ---- stage weights (swizzled by 16B chunk) ----
  const int nrows = isL1 ? 2 * CH : CH;
  for (int e = tid; e < nrows * 256; e += NTHR) {
    const int r = e >> 8, c16 = e & 255;
    const int phys = c16 ^ ((c16 >> 3) & 7);
    const float* src;
    if (!isL1)      src = Wrec0 + (size_t)(c * CH + r) * Hdim;
    else if (r < CH) src = Wrec1 + (size_t)(c * CH + r) * Hdim;
    else             src = Win1 + (size_t)(c * CH + r - CH) * Hdim;
    *(float4*)(smW + r * 1024 + phys * 4) = *(const float4*)(src + c16 * 4);
  }
  float* smP = smW + nrows * 1024;

  // ---- compute-role coords: tile rows {4hp..4hp+3} x b {4bp..4bp+3},
  //      k-slice ks (16-wide, interleaved) ----
  const int ks = tid & 15, hp = (tid >> 4) & 1, bp = tid >> 5;
  const float* wA = smW + (4 * hp) * 1024;          // rec rows
  const float* wB = smW + (CH + 4 * hp) * 1024;     // in rows (L1)
  const float* recS = (isL1 ? states1 : states0) + (size_t)(4 * bp) * TH;
  const float* inS  = states0 + (size_t)(4 * bp) * TH;

  // ---- owner-role coords: thread owns output (h_off, b), row == tid ----
  const int h_off = tid & 7, b = tid >> 3;
  const int h = c * CH + h_off;
  const float bias1 = isL1 ? b1[h] : 0.f;
  float* wr = (isL1 ? states1 : states0) + (size_t)b * TH + h;
  const __hip_bfloat16* x0p = X0 + (size_t)b * TH + h;
  const float* prow = smP + tid * PROW;
  float v = 0.f;
  __syncthreads();

  unsigned phase = 1;
  for (int p = 0; p <= Tlen; ++p) {
    // ---- scatter phase ----
    if (!isL1) {
      if (p > 0 && p < Tlen) {
        FOR_BI(DECL_ACC)
        const float* frA = recS + (size_t)(p - 1) * Hdim;
        DOT_TILE(wA, frA)
        const bool wrp = (ks & 1) == 0;
        const int col = ks >> 1;
        FOR_BI(FOLD)
      }
    } else if (p >= 1) {
      const int t = p - 1;
      FOR_BI(DECL_ACC)
      if (t > 0) {
        const float* frA = recS + (size_t)(t - 1) * Hdim;
        DOT_TILE(wA, frA)
      }
      {
        const float* frB = inS + (size_t)t * Hdim;
        DOT_TILE(wB, frB)
      }
      const bool wrp = (ks & 1) == 0;
      const int col = ks >> 1;
      FOR_BI(FOLD)
    }
    __syncthreads();
    // ---- gather + v update + store ----
    if (!isL1) {
      if (p < Tlen) {
        const float dotv = (p > 0) ? gather8(prow) : 0.f;
        const float accv = __bfloat162float(x0p[(size_t)p * Hdim]) + dotv;
        v = 0.9f * v + 0.1f * accv;
        __hip_atomic_store(wr + (size_t)p * Hdim, fmaxf(v, 0.f),
                           __ATOMIC_RELAXED, __HIP_MEMORY_SCOPE_AGENT);
      }
    } else if (p >= 1) {
      const int t = p - 1;
      const float accv = bias1 + gather8(prow);
      v = 0.9f * v + 0.1f * accv;
      __hip_atomic_store(wr + (size_t)t * Hdim, fmaxf(v, 0.f),
                         __ATOMIC_RELAXED, __HIP_MEMORY_SCOPE_AGENT);
    }
    if (p < Tlen) { gbarrier(bar, phase); ++phase; }
  }
}

// C[n,m] = sum_k A[n,k]*Bm[m,k] + bias[m]; 64x64 tile, fp32, out fp32 or bf16
template <bool OUT_BF16>
__global__ void __launch_bounds__(256)
gemm_nt(const float* __restrict__ A, const float* __restrict__ Bm,
        const float* __restrict__ bias, void* __restrict__ Cout,
        int N, int M, int K) {
  __shared__ float As[32][68];
  __shared__ float Bs[32][68];
  const int tid = threadIdx.x;
  const int tx = tid & 15, ty = tid >> 4;
  const int n0 = blockIdx.x * 64, m0 = blockIdx.y * 64;
  float acc[4][4] = {};
  for (int k0 = 0; k0 < K; k0 += 32) {
#pragma unroll
    for (int l = 0; l < 2; ++l) {
      const int idx = tid + l * 256;
      const int row = idx >> 3;
      const int col = (idx & 7) << 2;
      const float4 av = *(const float4*)&A[(size_t)(n0 + row) * K + k0 + col];
      As[col + 0][row] = av.x; As[col + 1][row] = av.y;
      As[col + 2][row] = av.z; As[col + 3][row] = av.w;
      const float4 bv = *(const float4*)&Bm[(size_t)(m0 + row) * K + k0 + col];
      Bs[col + 0][row] = bv.x; Bs[col + 1][row] = bv.y;
      Bs[col + 2][row] = bv.z; Bs[col + 3][row] = bv.w;
    }
    __syncthreads();
#pragma unroll
    for (int k = 0; k < 32; ++k) {
      float a[4], bb[4];
      *(float4*)a  = *(const float4*)&As[k][ty * 4];
      *(float4*)bb = *(const float4*)&Bs[k][tx * 4];
#pragma unroll
      for (int i = 0; i < 4; ++i)
#pragma unroll
        for (int j = 0; j < 4; ++j) acc[i][j] = fmaf(a[i], bb[j], acc[i][j]);
    }
    __syncthreads();
  }
#pragma unroll
  for (int i = 0; i < 4; ++i) {
    const size_t n = n0 + ty * 4 + i;
#pragma unroll
    for (int j = 0; j < 4; ++j) {
      const int m = m0 + tx * 4 + j;
      const float val = acc[i][j] + (bias ? bias[m] : 0.f);
      if (OUT_BF16) ((__hip_bfloat16*)Cout)[n * M + m] = __float2bfloat16(val);
      else          ((float*)Cout)[n * M + m] = val;
    }
  }
}

extern "C" void kernel_launch(void* const* d_in, const int* in_sizes, int n_in,
                              void* d_out, int out_size, void* d_ws, size_t ws_size,
                              hipStream_t stream) {
  const float* x     = (const float*)d_in[0];
  const float* Win0  = (const float*)d_in[1];
  const float* Wrec0 = (const float*)d_in[2];
  const float* b0    = (const float*)d_in[3];
  const float* Win1  = (const float*)d_in[4];
  const float* Wrec1 = (const float*)d_in[5];
  const float* b1    = (const float*)d_in[6];
  const float* Wout  = (const float*)d_in[7];
  const float* bout  = (const float*)d_in[8];

  float* out     = (float*)d_out;
  float* states0 = out + (size_t)Bsz * Tlen * DOUT;
  float* states1 = states0 + (size_t)Bsz * Tlen * Hdim;

  unsigned* bar = (unsigned*)d_ws;  // root at [0]; 32 leaves at [32 + 32*i]
  __hip_bfloat16* X0 = (__hip_bfloat16*)((char*)d_ws + 16384);
  const size_t need = 16384 + (size_t)Bsz * Tlen * Hdim * sizeof(__hip_bfloat16);
  if (ws_size < need) return;

  hipMemsetAsync(d_ws, 0, 16384, stream);  // zero barrier counters

  // X0[b*T+t, h] = x[b,t,:] @ W_in0^T + b0   (bf16, hoisted out of the scan)
  gemm_nt<true><<<dim3((Bsz * Tlen) / 64, Hdim / 64), 256, 0, stream>>>(
      x, Win0, b0, (void*)X0, Bsz * Tlen, Hdim, DIN);

  // dyn-LDS: L1 weights 16*1024*4 = 65536B + partials 512*9*4 = 18432B
  //        = 83968B  (> 81920 -> forces 1 block/CU)
  const int lds_bytes = 16 * 1024 * 4 + NTHR * PROW * 4;
  hipFuncSetAttribute((const void*)rnn_recurrent,
                      hipFuncAttributeMaxDynamicSharedMemorySize, lds_bytes);
  rnn_recurrent<<<NBLK, NTHR, lds_bytes, stream>>>(
      Wrec0, Wrec1, Win1, b1, X0, states0, states1, bar);

  // output = states1 @ W_out^T + b_out
  gemm_nt<false><<<dim3((Bsz * Tlen) / 64, DOUT / 64), 256, 0, stream>>>(
      states1, Wout, bout, (void*)out, Bsz * Tlen, DOUT, Hdim);
}

// Round 6
// 5652.013 us; speedup vs baseline: 7.0225x; 7.0225x over previous
//
#include <hip/hip_runtime.h>
#include <hip/hip_fp16.h>

// Leaky 2-layer CTRNN, B=64 T=512 D_IN=256 H=1024 D_OUT=256, alpha=0.1.
// Round 8: MFMA persistent kernel (structural rewrite).
//  Rounds 3-7 post-mortem: every VALU register-tile variant pinned VGPR at
//  exactly 128 and spilled (pre-RA scheduler hoists the unrolled loop's
//  independent loads; bigger unroll = more spill: r7 WRITE 59GB > r5 37GB),
//  and scratch thrashed L2 (FETCH 68GB vs 1.35GB in spill-free r2).
//  MfmaUtil was 0.0 all session for a matmul-shaped op. Rewrite:
//   - per block: 16 h x 32 b; D = mfma_f32_16x16x32_f16 tiles (rows=batch,
//     cols=h, fully used). A = fr ring (f16, global), B = W (f16 LDS, row
//     stride 1032 pads banks). Per L1 CU per phase: 128 ds_read_b128 +
//     128 global dwordx4 + 128 MFMA (vs 4096+4096 VALU-path instrs in r2).
//   - fr states live in a depth-2 f16 ring (agent-scope ushort stores);
//     f32 states are plain stores (read only by the follow-up gemm).
//   - 8 waves = 2 batch-tiles x 4 partials (L1: dot x k-half; L0: k-quarter),
//     combined in an 8KB LDS P buffer; owner (b,h)=tid keeps the v carry.
//   - per-wave live set ~40 VGPR, unroll capped at 2 -> no spill possible.
//   - barrier/phase schedule identical to the verified r2 structure.
//  f16 everywhere (X0 + ring) instead of bf16: absmax should improve.

using half8 = __attribute__((ext_vector_type(8))) _Float16;
using f32x4 = __attribute__((ext_vector_type(4))) float;

constexpr int Bsz = 64, Tlen = 512, DIN = 256, Hdim = 1024, DOUT = 256;
constexpr int NBLK = 256;           // persistent, 1 per CU
constexpr int NTHR = 512;           // 8 waves
constexpr int CH = 16;              // h rows per block
constexpr int BB = 32;              // batches per block
constexpr int WROW = 1032;          // LDS W row stride (f16): pads banks
constexpr int TH = Tlen * Hdim;     // per-batch state stride (elems)
constexpr size_t RSLOT = 2 * 64 * 1024;  // f16 elems per ring slot (2 layers)

__device__ __forceinline__ void gbarrier(unsigned* bar, unsigned phase) {
  __builtin_amdgcn_s_waitcnt(0);            // drain stores before arrival
  __syncthreads();
  if (threadIdx.x == 0) {
    unsigned* leaf = bar + 32 + (blockIdx.x & 31) * 32;   // 128B-padded leaves
    unsigned old = __hip_atomic_fetch_add(leaf, 1u, __ATOMIC_RELAXED,
                                          __HIP_MEMORY_SCOPE_AGENT);
    if ((old & 7u) == 7u)                   // 8th arrival at this leaf
      __hip_atomic_fetch_add(bar, 1u, __ATOMIC_RELAXED, __HIP_MEMORY_SCOPE_AGENT);
    while (__hip_atomic_load(bar, __ATOMIC_RELAXED, __HIP_MEMORY_SCOPE_AGENT) <
           phase * 32u)
      __builtin_amdgcn_s_sleep(4);
    __builtin_amdgcn_fence(__ATOMIC_ACQUIRE, "agent");  // one buffer_inv
  }
  __syncthreads();
}

__device__ __forceinline__ void store_f16_agent(_Float16* p, float v) {
  const unsigned short bits = __builtin_bit_cast(unsigned short, (_Float16)v);
  __hip_atomic_store((unsigned short*)p, bits, __ATOMIC_RELAXED,
                     __HIP_MEMORY_SCOPE_AGENT);
}

__global__ void __launch_bounds__(NTHR)
rnn_recurrent(const float* __restrict__ Wrec0, const float* __restrict__ Wrec1,
              const float* __restrict__ Win1,  const float* __restrict__ b1,
              const _Float16* __restrict__ X0,
              float* __restrict__ states0, float* __restrict__ states1,
              _Float16* __restrict__ ring, unsigned* __restrict__ bar) {
  extern __shared__ char smem[];
  _Float16* mat0 = (_Float16*)smem;              // [16][WROW] f16
  _Float16* mat1 = mat0 + CH * WROW;             // [16][WROW] f16 (L1 only)
  float* P = (float*)(smem + 2 * CH * WROW * sizeof(_Float16));  // [2][16][16][4]

  const int bid = blockIdx.x, tid = threadIdx.x;
  const bool isL1 = bid >= 128;
  const int idx = bid & 127;
  const int h0 = (idx & 63) * CH;      // h chunk
  const int B0 = (idx >> 6) * BB;      // batch half

  // ---- stage weights as f16 into LDS (one-time) ----
  if (!isL1) {
    for (int e = tid; e < CH * Hdim; e += NTHR) {
      const int r = e >> 10, k = e & 1023;
      mat0[r * WROW + k] = (_Float16)Wrec0[(size_t)(h0 + r) * Hdim + k];
    }
  } else {
    for (int e = tid; e < CH * Hdim; e += NTHR) {
      const int r = e >> 10, k = e & 1023;
      mat0[r * WROW + k] = (_Float16)Win1[(size_t)(h0 + r) * Hdim + k];
      mat1[r * WROW + k] = (_Float16)Wrec1[(size_t)(h0 + r) * Hdim + k];
    }
  }

  // ---- compute-wave coords: wave w = (bt = w&1, part = w>>1) ----
  //  L1: part = (kh<<1)|d : d=0 -> Win1 * fr0[t], d=1 -> Wrec1 * fr1[t-1]
  //  L0: part = kq (k quarter)
  const int l = tid & 63, w = tid >> 6;
  const int bt = w & 1, part = w >> 1;
  const int d = part & 1;
  const int koff = (l >> 4) * 8;
  const int kbase = isL1 ? (part >> 1) * 512 : part * 256;
  const _Float16* bp0 =
      ((isL1 && d) ? mat1 : mat0) + (size_t)(l & 15) * WROW + kbase + koff;
  const int rlayer = (isL1 && d) ? 1 : 0;
  const _Float16* ap0 =
      ring + ((size_t)rlayer * 64 + (B0 + bt * 16 + (l & 15))) * 1024 + kbase + koff;

  // ---- owner coords: thread owns output (h_off, bo) ----
  const int h_off = tid & 15, bo = (tid >> 4) & 31;
  const int b = B0 + bo, h = h0 + h_off;
  const float bias1 = isL1 ? b1[h] : 0.f;
  const float* pown = P + (((bo >> 4) * 16 + (bo & 15)) * 16 + h_off) * 4;
  float* stp = (isL1 ? states1 : states0) + (size_t)b * TH + h;
  const _Float16* x0p = X0 + (size_t)b * TH + h;
  _Float16* ringw = ring + ((size_t)(isL1 ? 1 : 0) * 64 + b) * 1024 + h;
  float v = 0.f;
  __syncthreads();

  unsigned phase = 1;
  for (int p = 0; p <= Tlen; ++p) {
    const bool active = isL1 ? (p >= 1) : (p < Tlen);
    f32x4 acc = {0.f, 0.f, 0.f, 0.f};
    if (active) {
      bool dv; int slot;
      if (!isL1)   { dv = p >= 1; slot = (p - 1) & 1; }  // fr0[p-1]
      else if (!d) { dv = true;   slot = (p - 1) & 1; }  // fr0[t=p-1]
      else         { dv = p >= 2; slot = p & 1; }        // fr1[t-1=p-2]
      if (dv) {
        const _Float16* ap = ap0 + (size_t)slot * RSLOT;
        const _Float16* bp = bp0;
        if (isL1) {
#pragma unroll 2
          for (int s = 0; s < 16; ++s) {
            acc = __builtin_amdgcn_mfma_f32_16x16x32_f16(
                *(const half8*)ap, *(const half8*)bp, acc, 0, 0, 0);
            ap += 32; bp += 32;
          }
        } else {
#pragma unroll 2
          for (int s = 0; s < 8; ++s) {
            acc = __builtin_amdgcn_mfma_f32_16x16x32_f16(
                *(const half8*)ap, *(const half8*)bp, acc, 0, 0, 0);
            ap += 32; bp += 32;
          }
        }
      }
      // D lane l: col = l&15 (=h_rel), row = (l>>4)*4 + reg (=batch in tile)
      float* pw = P + (((bt * 16 + (l >> 4) * 4) * 16) + (l & 15)) * 4 + part;
      pw[0] = acc.x; pw[64] = acc.y; pw[128] = acc.z; pw[192] = acc.w;
    }
    __syncthreads();
    if (active) {
      const int t = isL1 ? p - 1 : p;
      const f32x4 pv = *(const f32x4*)pown;
      float accv = (pv.x + pv.y) + (pv.z + pv.w);
      accv += isL1 ? bias1 : (float)x0p[(size_t)t * Hdim];
      v = 0.9f * v + 0.1f * accv;
      const float fr = fmaxf(v, 0.f);
      stp[(size_t)t * Hdim] = fr;                       // plain f32 (output only)
      store_f16_agent(ringw + (size_t)(t & 1) * RSLOT, fr);  // scan operand
    }
    if (p < Tlen) { gbarrier(bar, phase); ++phase; }
  }
}

// C[n,m] = sum_k A[n,k]*Bm[m,k] + bias[m]; 64x64 tile, fp32, out fp32 or f16
template <bool OUT_HALF>
__global__ void __launch_bounds__(256)
gemm_nt(const float* __restrict__ A, const float* __restrict__ Bm,
        const float* __restrict__ bias, void* __restrict__ Cout,
        int N, int M, int K) {
  __shared__ float As[32][68];
  __shared__ float Bs[32][68];
  const int tid = threadIdx.x;
  const int tx = tid & 15, ty = tid >> 4;
  const int n0 = blockIdx.x * 64, m0 = blockIdx.y * 64;
  float acc[4][4] = {};
  for (int k0 = 0; k0 < K; k0 += 32) {
#pragma unroll
    for (int l = 0; l < 2; ++l) {
      const int idx = tid + l * 256;
      const int row = idx >> 3;
      const int col = (idx & 7) << 2;
      const float4 av = *(const float4*)&A[(size_t)(n0 + row) * K + k0 + col];
      As[col + 0][row] = av.x; As[col + 1][row] = av.y;
      As[col + 2][row] = av.z; As[col + 3][row] = av.w;
      const float4 bv = *(const float4*)&Bm[(size_t)(m0 + row) * K + k0 + col];
      Bs[col + 0][row] = bv.x; Bs[col + 1][row] = bv.y;
      Bs[col + 2][row] = bv.z; Bs[col + 3][row] = bv.w;
    }
    __syncthreads();
#pragma unroll
    for (int k = 0; k < 32; ++k) {
      float a[4], bb[4];
      *(float4*)a  = *(const float4*)&As[k][ty * 4];
      *(float4*)bb = *(const float4*)&Bs[k][tx * 4];
#pragma unroll
      for (int i = 0; i < 4; ++i)
#pragma unroll
        for (int j = 0; j < 4; ++j) acc[i][j] = fmaf(a[i], bb[j], acc[i][j]);
    }
    __syncthreads();
  }
#pragma unroll
  for (int i = 0; i < 4; ++i) {
    const size_t n = n0 + ty * 4 + i;
#pragma unroll
    for (int j = 0; j < 4; ++j) {
      const int m = m0 + tx * 4 + j;
      const float val = acc[i][j] + (bias ? bias[m] : 0.f);
      if (OUT_HALF) ((_Float16*)Cout)[n * M + m] = (_Float16)val;
      else          ((float*)Cout)[n * M + m] = val;
    }
  }
}

extern "C" void kernel_launch(void* const* d_in, const int* in_sizes, int n_in,
                              void* d_out, int out_size, void* d_ws, size_t ws_size,
                              hipStream_t stream) {
  const float* x     = (const float*)d_in[0];
  const float* Win0  = (const float*)d_in[1];
  const float* Wrec0 = (const float*)d_in[2];
  const float* b0    = (const float*)d_in[3];
  const float* Win1  = (const float*)d_in[4];
  const float* Wrec1 = (const float*)d_in[5];
  const float* b1    = (const float*)d_in[6];
  const float* Wout  = (const float*)d_in[7];
  const float* bout  = (const float*)d_in[8];

  float* out     = (float*)d_out;
  float* states0 = out + (size_t)Bsz * Tlen * DOUT;
  float* states1 = states0 + (size_t)Bsz * Tlen * Hdim;

  unsigned* bar = (unsigned*)d_ws;  // root at [0]; 32 leaves at [32 + 32*i]
  _Float16* X0 = (_Float16*)((char*)d_ws + 16384);
  _Float16* ring = X0 + (size_t)Bsz * Tlen * Hdim;
  const size_t need = 16384 + (size_t)Bsz * Tlen * Hdim * 2 + 2 * RSLOT * 2;
  if (ws_size < need) return;

  hipMemsetAsync(d_ws, 0, 16384, stream);  // zero barrier counters

  // X0[b*T+t, h] = x[b,t,:] @ W_in0^T + b0   (f16, hoisted out of the scan)
  gemm_nt<true><<<dim3((Bsz * Tlen) / 64, Hdim / 64), 256, 0, stream>>>(
      x, Win0, b0, (void*)X0, Bsz * Tlen, Hdim, DIN);

  // dyn-LDS actually used: 2*16*1032*2 = 66048 + P 8192 = 74240.
  // Request 86016 (> 81920) to force 1 block/CU for the persistent grid.
  const int lds_bytes = 86016;
  hipFuncSetAttribute((const void*)rnn_recurrent,
                      hipFuncAttributeMaxDynamicSharedMemorySize, lds_bytes);
  rnn_recurrent<<<NBLK, NTHR, lds_bytes, stream>>>(
      Wrec0, Wrec1, Win1, b1, X0, states0, states1, ring, bar);

  // output = states1 @ W_out^T + b_out
  gemm_nt<false><<<dim3((Bsz * Tlen) / 64, DOUT / 64), 256, 0, stream>>>(
      states1, Wout, bout, (void*)out, Bsz * Tlen, DOUT, Hdim);
}